// Round 1
// baseline (284.904 us; speedup 1.0000x reference)
//
#include <hip/hip_runtime.h>
#include <hip/hip_bf16.h>
#include <cstdint>

typedef __bf16 bf16_t;
typedef __bf16 bf16x8 __attribute__((ext_vector_type(8)));
typedef float f32x4 __attribute__((ext_vector_type(4)));

#define B_ 4
#define S_ 4096
#define E_ 1024
#define L_ 64

__device__ __forceinline__ f32x4 mfma16(bf16x8 a, bf16x8 b, f32x4 c) {
  return __builtin_amdgcn_mfma_f32_16x16x32_bf16(a, b, c, 0, 0, 0);
}

// ---- kernel 1: weights -> Wt bf16 [192][1024] (Wt[n][k] = W[k][n]) ----
__global__ void prep_w_kernel(const float* __restrict__ Wq, const float* __restrict__ Wk,
                              const float* __restrict__ Wv, bf16_t* __restrict__ Wt) {
  int n = blockIdx.x;  // 0..191
  const float* W = (n < 64) ? Wq : (n < 128 ? Wk : Wv);
  int col = n & 63;
  for (int k = threadIdx.x; k < E_; k += blockDim.x)
    Wt[(size_t)n * E_ + k] = (bf16_t)W[(size_t)k * L_ + col];
}

// ---- kernel 2: QKV projection via bf16 MFMA, fp32 accum ----
// Q,K stored [B*S][64] bf16 row-major; V stored transposed Vt[b][64][4096] bf16.
__global__ __launch_bounds__(256) void qkv_proj_kernel(
    const float* __restrict__ x, const bf16_t* __restrict__ Wt,
    const float* __restrict__ bq, const float* __restrict__ bk, const float* __restrict__ bv,
    bf16_t* __restrict__ Q, bf16_t* __restrict__ K, bf16_t* __restrict__ Vt) {
  const int w = threadIdx.x >> 6, l = threadIdx.x & 63;
  const int lr = l & 15, lg = l >> 4;
  const int m0 = blockIdx.x * 64 + w * 16;   // 16-row strip per wave

  f32x4 acc[12];
#pragma unroll
  for (int t = 0; t < 12; ++t) acc[t] = f32x4{0.f, 0.f, 0.f, 0.f};

  const float* xrow = x + (size_t)(m0 + lr) * E_ + lg * 8;
#pragma unroll 2
  for (int kc = 0; kc < E_; kc += 32) {
    float4 a0 = *reinterpret_cast<const float4*>(xrow + kc);
    float4 a1 = *reinterpret_cast<const float4*>(xrow + kc + 4);
    bf16x8 a;
    a[0] = (bf16_t)a0.x; a[1] = (bf16_t)a0.y; a[2] = (bf16_t)a0.z; a[3] = (bf16_t)a0.w;
    a[4] = (bf16_t)a1.x; a[5] = (bf16_t)a1.y; a[6] = (bf16_t)a1.z; a[7] = (bf16_t)a1.w;
#pragma unroll
    for (int t = 0; t < 12; ++t) {
      bf16x8 b = *reinterpret_cast<const bf16x8*>(Wt + (size_t)(t * 16 + lr) * E_ + kc + lg * 8);
      acc[t] = mfma16(a, b, acc[t]);
    }
  }

#pragma unroll
  for (int t = 0; t < 12; ++t) {
    int ng = t * 16 + lr;          // 0..191 global out col
    int mat = ng >> 6;             // wave-uniform per t
    int col = ng & 63;
    const float* bias = (mat == 0) ? bq : (mat == 1 ? bk : bv);
    float bb = bias[col];
#pragma unroll
    for (int r = 0; r < 4; ++r) {
      int mg = m0 + lg * 4 + r;    // global row (batch*4096 + s)
      float v = acc[t][r] + bb;
      if (mat == 0)      Q[(size_t)mg * L_ + col] = (bf16_t)v;
      else if (mat == 1) K[(size_t)mg * L_ + col] = (bf16_t)v;
      else {
        int batch = mg >> 12, s = mg & (S_ - 1);
        Vt[((size_t)batch * L_ + col) * S_ + s] = (bf16_t)v;
      }
    }
  }
}

// ---- kernel 3: causal flash attention ----
// grid = 4 batches * 64 q-tiles; block = 4 waves, each wave a 16-row q-strip.
__global__ __launch_bounds__(256) void attn_kernel(
    const bf16_t* __restrict__ Qg, const bf16_t* __restrict__ Kg,
    const bf16_t* __restrict__ Vt, float* __restrict__ out) {
  __shared__ __align__(16) bf16_t plds[4][16 * 72];  // padded stride 72 -> 2-way (free)
  const int w = threadIdx.x >> 6, l = threadIdx.x & 63;
  const int lr = l & 15, lg = l >> 4;
  const int batch = blockIdx.x >> 6;
  const int qt = blockIdx.x & 63;
  const int qrow = qt * 64 + w * 16;                 // batch-local
  const size_t qbase = (size_t)batch * S_ + qrow;
  const bf16_t* Kb = Kg + (size_t)batch * S_ * L_;
  const bf16_t* Vb = Vt + (size_t)batch * L_ * S_;
  bf16_t* pw = plds[w];

  // Q fragments hoisted (16 rows x 64 k)
  bf16x8 qa0 = *reinterpret_cast<const bf16x8*>(Qg + (qbase + lr) * L_ + lg * 8);
  bf16x8 qa1 = *reinterpret_cast<const bf16x8*>(Qg + (qbase + lr) * L_ + 32 + lg * 8);

  f32x4 o[4];
  float m[4], ssum[4];
#pragma unroll
  for (int r = 0; r < 4; ++r) { o[r] = f32x4{0.f, 0.f, 0.f, 0.f}; m[r] = -1e30f; ssum[r] = 0.f; }

  for (int kt = 0; kt <= qt; ++kt) {
    const int t0 = kt * 64;
    // S = Q K^T (16 x 64 tile per wave)
    f32x4 st[4];
#pragma unroll
    for (int cf = 0; cf < 4; ++cf) st[cf] = f32x4{0.f, 0.f, 0.f, 0.f};
#pragma unroll
    for (int cf = 0; cf < 4; ++cf) {
      const bf16_t* krow = Kb + (size_t)(t0 + cf * 16 + lr) * L_ + lg * 8;
      st[cf] = mfma16(qa0, *reinterpret_cast<const bf16x8*>(krow), st[cf]);
      st[cf] = mfma16(qa1, *reinterpret_cast<const bf16x8*>(krow + 32), st[cf]);
    }
    const bool diag = (kt == qt);
    float p[4][4];  // [cf][reg]
#pragma unroll
    for (int r = 0; r < 4; ++r) {
      const int qg = qrow + lg * 4 + r;
      float rowmax = -1e30f;
#pragma unroll
      for (int cf = 0; cf < 4; ++cf) {
        float s = st[cf][r] * 0.125f;  // 1/sqrt(64)
        if (diag && (t0 + cf * 16 + lr) > qg) s = -1e30f;
        p[cf][r] = s;
        rowmax = fmaxf(rowmax, s);
      }
      rowmax = fmaxf(rowmax, __shfl_xor(rowmax, 1));
      rowmax = fmaxf(rowmax, __shfl_xor(rowmax, 2));
      rowmax = fmaxf(rowmax, __shfl_xor(rowmax, 4));
      rowmax = fmaxf(rowmax, __shfl_xor(rowmax, 8));
      float mnew = fmaxf(m[r], rowmax);
      float scale = __expf(m[r] - mnew);
      float rs = 0.f;
#pragma unroll
      for (int cf = 0; cf < 4; ++cf) {
        float e = __expf(p[cf][r] - mnew);
        p[cf][r] = e;
        rs += e;
      }
      rs += __shfl_xor(rs, 1);
      rs += __shfl_xor(rs, 2);
      rs += __shfl_xor(rs, 4);
      rs += __shfl_xor(rs, 8);
      ssum[r] = ssum[r] * scale + rs;
#pragma unroll
      for (int cf = 0; cf < 4; ++cf) o[cf][r] *= scale;
      m[r] = mnew;
    }
    // P (C-layout) -> LDS -> A-layout fragments
#pragma unroll
    for (int r = 0; r < 4; ++r)
#pragma unroll
      for (int cf = 0; cf < 4; ++cf)
        pw[(lg * 4 + r) * 72 + cf * 16 + lr] = (bf16_t)p[cf][r];
    bf16x8 pa0 = *reinterpret_cast<const bf16x8*>(pw + lr * 72 + lg * 8);
    bf16x8 pa1 = *reinterpret_cast<const bf16x8*>(pw + lr * 72 + 32 + lg * 8);
    // O += P V  (V read from transposed layout, contiguous 16B)
#pragma unroll
    for (int cf = 0; cf < 4; ++cf) {
      const bf16_t* vrow = Vb + (size_t)(cf * 16 + lr) * S_ + t0 + lg * 8;
      o[cf] = mfma16(pa0, *reinterpret_cast<const bf16x8*>(vrow), o[cf]);
      o[cf] = mfma16(pa1, *reinterpret_cast<const bf16x8*>(vrow + 32), o[cf]);
    }
  }

  float inv[4];
#pragma unroll
  for (int r = 0; r < 4; ++r) inv[r] = 1.f / ssum[r];
#pragma unroll
  for (int cf = 0; cf < 4; ++cf)
#pragma unroll
    for (int r = 0; r < 4; ++r)
      out[(qbase + lg * 4 + r) * L_ + cf * 16 + lr] = o[cf][r] * inv[r];
}

extern "C" void kernel_launch(void* const* d_in, const int* in_sizes, int n_in,
                              void* d_out, int out_size, void* d_ws, size_t ws_size,
                              hipStream_t stream) {
  (void)in_sizes; (void)n_in; (void)out_size; (void)ws_size;
  const float* x  = (const float*)d_in[0];
  const float* Wq = (const float*)d_in[1];
  const float* Wk = (const float*)d_in[2];
  const float* Wv = (const float*)d_in[3];
  const float* bq = (const float*)d_in[4];
  const float* bk = (const float*)d_in[5];
  const float* bv = (const float*)d_in[6];
  // d_in[7] = mask; it is tril(ones) by construction -> causal hard-coded.
  float* out = (float*)d_out;

  char* ws = (char*)d_ws;
  bf16_t* Q  = (bf16_t*)(ws + 0);                       // 2 MiB
  bf16_t* K  = (bf16_t*)(ws + (size_t)2 * 1024 * 1024); // 2 MiB
  bf16_t* Vt = (bf16_t*)(ws + (size_t)4 * 1024 * 1024); // 2 MiB
  bf16_t* Wt = (bf16_t*)(ws + (size_t)6 * 1024 * 1024); // 384 KiB

  hipLaunchKernelGGL(prep_w_kernel, dim3(192), dim3(256), 0, stream, Wq, Wk, Wv, Wt);
  hipLaunchKernelGGL(qkv_proj_kernel, dim3(16384 / 64), dim3(256), 0, stream,
                     x, Wt, bq, bk, bv, Q, K, Vt);
  hipLaunchKernelGGL(attn_kernel, dim3(B_ * (S_ / 64)), dim3(256), 0, stream, Q, K, Vt, out);
}

// Round 2
// 186.401 us; speedup vs baseline: 1.5284x; 1.5284x over previous
//
#include <hip/hip_runtime.h>
#include <hip/hip_bf16.h>
#include <cstdint>

typedef __bf16 bf16_t;
typedef __bf16 bf16x8 __attribute__((ext_vector_type(8)));
typedef float f32x4 __attribute__((ext_vector_type(4)));

#define B_ 4
#define S_ 4096
#define E_ 1024
#define L_ 64

__device__ __forceinline__ f32x4 mfma16(bf16x8 a, bf16x8 b, f32x4 c) {
  return __builtin_amdgcn_mfma_f32_16x16x32_bf16(a, b, c, 0, 0, 0);
}

// ---- kernel 1: weights -> Wt bf16 [192][1024] (Wt[n][k] = W[k][n]) ----
__global__ void prep_w_kernel(const float* __restrict__ Wq, const float* __restrict__ Wk,
                              const float* __restrict__ Wv, bf16_t* __restrict__ Wt) {
  int n = blockIdx.x;  // 0..191
  const float* W = (n < 64) ? Wq : (n < 128 ? Wk : Wv);
  int col = n & 63;
  for (int k = threadIdx.x; k < E_; k += blockDim.x)
    Wt[(size_t)n * E_ + k] = (bf16_t)W[(size_t)k * L_ + col];
}

// ---- kernel 2: QKV projection via bf16 MFMA, fp32 accum ----
// 512 blocks x 4 waves: wave = (rowhalf, colhalf); 16 rows x 96 cols each.
// Q,K stored [B*S][64] bf16 row-major; V stored transposed Vt[b][64][4096] bf16.
__global__ __launch_bounds__(256) void qkv_proj_kernel(
    const float* __restrict__ x, const bf16_t* __restrict__ Wt,
    const float* __restrict__ bq, const float* __restrict__ bk, const float* __restrict__ bv,
    bf16_t* __restrict__ Q, bf16_t* __restrict__ K, bf16_t* __restrict__ Vt) {
  const int w = threadIdx.x >> 6, l = threadIdx.x & 63;
  const int lr = l & 15, lg = l >> 4;
  const int m0 = blockIdx.x * 32 + (w & 1) * 16;  // 16-row strip
  const int colbase = (w >> 1) * 96;              // 6 col-tiles of 16

  f32x4 acc[6];
#pragma unroll
  for (int t = 0; t < 6; ++t) acc[t] = f32x4{0.f, 0.f, 0.f, 0.f};

  const float* xrow = x + (size_t)(m0 + lr) * E_ + lg * 8;
#pragma unroll 2
  for (int kc = 0; kc < E_; kc += 32) {
    float4 a0 = *reinterpret_cast<const float4*>(xrow + kc);
    float4 a1 = *reinterpret_cast<const float4*>(xrow + kc + 4);
    bf16x8 a;
    a[0] = (bf16_t)a0.x; a[1] = (bf16_t)a0.y; a[2] = (bf16_t)a0.z; a[3] = (bf16_t)a0.w;
    a[4] = (bf16_t)a1.x; a[5] = (bf16_t)a1.y; a[6] = (bf16_t)a1.z; a[7] = (bf16_t)a1.w;
#pragma unroll
    for (int t = 0; t < 6; ++t) {
      bf16x8 b = *reinterpret_cast<const bf16x8*>(Wt + (size_t)(colbase + t * 16 + lr) * E_ + kc + lg * 8);
      acc[t] = mfma16(a, b, acc[t]);
    }
  }

#pragma unroll
  for (int t = 0; t < 6; ++t) {
    int ng = colbase + t * 16 + lr;  // 0..191 global out col
    int mat = ng >> 6;               // wave-uniform per t (16 | 64)
    int col = ng & 63;
    const float* bias = (mat == 0) ? bq : (mat == 1 ? bk : bv);
    float bb = bias[col];
#pragma unroll
    for (int r = 0; r < 4; ++r) {
      int mg = m0 + lg * 4 + r;  // global row (batch*4096 + s)
      float v = acc[t][r] + bb;
      if (mat == 0)      Q[(size_t)mg * L_ + col] = (bf16_t)v;
      else if (mat == 1) K[(size_t)mg * L_ + col] = (bf16_t)v;
      else {
        int batch = mg >> 12, s = mg & (S_ - 1);
        Vt[((size_t)batch * L_ + col) * S_ + s] = (bf16_t)v;
      }
    }
  }
}

// ---- kernel 3: causal flash attention, intra-block K-split ----
// grid = 256 blocks (batch XCD-affine), 1024 threads = 16 waves.
// wave w: row-strip r = w&3 (16 rows), K-chunk c = w>>2 (tiles kt ≡ c mod 4).
// End: LDS combine of the 4 chunks per strip (online-softmax merge).
__global__ __launch_bounds__(1024) void attn_kernel(
    const bf16_t* __restrict__ Qg, const bf16_t* __restrict__ Kg,
    const bf16_t* __restrict__ Vt, float* __restrict__ out) {
  // od region doubles as per-wave P staging during the loop (private per wave).
  __shared__ __align__(16) float od_lds[12 * 16 * 64];  // 48 KiB: chunks c=1..3 o-export
  __shared__ float ml_lds[16][16][2];                    // [wave][row][m,l]

  const int w = threadIdx.x >> 6, l = threadIdx.x & 63;
  const int lr = l & 15, lg = l >> 4;
  const int r = w & 3, c = w >> 2;
  // batch <-> XCD affinity: XCD = blockIdx%8 = 2*batch + (blockIdx&1)
  const int batch = (blockIdx.x >> 1) & 3;
  const int qt = ((blockIdx.x >> 3) << 1) | (blockIdx.x & 1);
  const int qrow = qt * 64 + r * 16;  // batch-local
  const size_t qbase = (size_t)batch * S_ + qrow;
  const bf16_t* Kb = Kg + (size_t)batch * S_ * L_;
  const bf16_t* Vb = Vt + (size_t)batch * L_ * S_;
  bf16_t* pw = reinterpret_cast<bf16_t*>(od_lds) + (size_t)w * (16 * 72);

  // Q fragments hoisted (16 rows x 64 k) — chunks of a strip load the same Q
  bf16x8 qa0 = *reinterpret_cast<const bf16x8*>(Qg + (qbase + lr) * L_ + lg * 8);
  bf16x8 qa1 = *reinterpret_cast<const bf16x8*>(Qg + (qbase + lr) * L_ + 32 + lg * 8);

  f32x4 o[4];
  float m[4], ssum[4];
#pragma unroll
  for (int rr = 0; rr < 4; ++rr) { o[rr] = f32x4{0.f, 0.f, 0.f, 0.f}; m[rr] = -1e30f; ssum[rr] = 0.f; }

  for (int kt = c; kt <= qt; kt += 4) {
    const int t0 = kt * 64;
    f32x4 st[4];
#pragma unroll
    for (int cf = 0; cf < 4; ++cf) st[cf] = f32x4{0.f, 0.f, 0.f, 0.f};
#pragma unroll
    for (int cf = 0; cf < 4; ++cf) {
      const bf16_t* krow = Kb + (size_t)(t0 + cf * 16 + lr) * L_ + lg * 8;
      st[cf] = mfma16(qa0, *reinterpret_cast<const bf16x8*>(krow), st[cf]);
      st[cf] = mfma16(qa1, *reinterpret_cast<const bf16x8*>(krow + 32), st[cf]);
    }
    const bool diag = (kt == qt);
    float p[4][4];  // [cf][reg]
#pragma unroll
    for (int rr = 0; rr < 4; ++rr) {
      const int qg = qrow + lg * 4 + rr;
      float rowmax = -1e30f;
#pragma unroll
      for (int cf = 0; cf < 4; ++cf) {
        float s = st[cf][rr] * 0.125f;  // 1/sqrt(64)
        if (diag && (t0 + cf * 16 + lr) > qg) s = -1e30f;
        p[cf][rr] = s;
        rowmax = fmaxf(rowmax, s);
      }
      rowmax = fmaxf(rowmax, __shfl_xor(rowmax, 1));
      rowmax = fmaxf(rowmax, __shfl_xor(rowmax, 2));
      rowmax = fmaxf(rowmax, __shfl_xor(rowmax, 4));
      rowmax = fmaxf(rowmax, __shfl_xor(rowmax, 8));
      float mnew = fmaxf(m[rr], rowmax);
      float scale = __expf(m[rr] - mnew);
      float rs = 0.f;
#pragma unroll
      for (int cf = 0; cf < 4; ++cf) {
        float e = __expf(p[cf][rr] - mnew);
        p[cf][rr] = e;
        rs += e;
      }
      rs += __shfl_xor(rs, 1);
      rs += __shfl_xor(rs, 2);
      rs += __shfl_xor(rs, 4);
      rs += __shfl_xor(rs, 8);
      ssum[rr] = ssum[rr] * scale + rs;
#pragma unroll
      for (int cf = 0; cf < 4; ++cf) o[cf][rr] *= scale;
      m[rr] = mnew;
    }
    // P (C-layout) -> LDS -> A-layout fragments (wave-private region)
#pragma unroll
    for (int rr = 0; rr < 4; ++rr)
#pragma unroll
      for (int cf = 0; cf < 4; ++cf)
        pw[(lg * 4 + rr) * 72 + cf * 16 + lr] = (bf16_t)p[cf][rr];
    bf16x8 pa0 = *reinterpret_cast<const bf16x8*>(pw + lr * 72 + lg * 8);
    bf16x8 pa1 = *reinterpret_cast<const bf16x8*>(pw + lr * 72 + 32 + lg * 8);
#pragma unroll
    for (int cf = 0; cf < 4; ++cf) {
      const bf16_t* vrow = Vb + (size_t)(cf * 16 + lr) * S_ + t0 + lg * 8;
      o[cf] = mfma16(pa0, *reinterpret_cast<const bf16x8*>(vrow), o[cf]);
      o[cf] = mfma16(pa1, *reinterpret_cast<const bf16x8*>(vrow + 32), o[cf]);
    }
  }

  // export per-chunk m,l (replicated across lr; lr==0 lanes write)
  if (lr == 0) {
#pragma unroll
    for (int rr = 0; rr < 4; ++rr) {
      ml_lds[w][lg * 4 + rr][0] = m[rr];
      ml_lds[w][lg * 4 + rr][1] = ssum[rr];
    }
  }
  __syncthreads();  // all P-staging reads done; od region now safe to overwrite
  if (c > 0) {
    float* dst = od_lds + (size_t)((c - 1) * 4 + r) * (16 * 64);
#pragma unroll
    for (int cf = 0; cf < 4; ++cf)
#pragma unroll
      for (int rr = 0; rr < 4; ++rr)
        dst[(lg * 4 + rr) * 64 + cf * 16 + lr] = o[cf][rr];
  }
  __syncthreads();
  if (c == 0) {
#pragma unroll
    for (int rr = 0; rr < 4; ++rr) {
      int row = lg * 4 + rr;
      float M = m[rr];
      float mv[3];
#pragma unroll
      for (int cc = 1; cc < 4; ++cc) {
        mv[cc - 1] = ml_lds[cc * 4 + r][row][0];
        M = fmaxf(M, mv[cc - 1]);
      }
      float f0 = __expf(m[rr] - M);
      float Lsum = ssum[rr] * f0;
      float fc[3];
#pragma unroll
      for (int cc = 1; cc < 4; ++cc) {
        fc[cc - 1] = __expf(mv[cc - 1] - M);
        Lsum += ml_lds[cc * 4 + r][row][1] * fc[cc - 1];
      }
      float invL = 1.f / Lsum;
#pragma unroll
      for (int cf = 0; cf < 4; ++cf) {
        float val = o[cf][rr] * f0;
#pragma unroll
        for (int cc = 1; cc < 4; ++cc)
          val += od_lds[(size_t)((cc - 1) * 4 + r) * (16 * 64) + row * 64 + cf * 16 + lr] * fc[cc - 1];
        out[(qbase + row) * L_ + cf * 16 + lr] = val * invL;
      }
    }
  }
}

extern "C" void kernel_launch(void* const* d_in, const int* in_sizes, int n_in,
                              void* d_out, int out_size, void* d_ws, size_t ws_size,
                              hipStream_t stream) {
  (void)in_sizes; (void)n_in; (void)out_size; (void)ws_size;
  const float* x  = (const float*)d_in[0];
  const float* Wq = (const float*)d_in[1];
  const float* Wk = (const float*)d_in[2];
  const float* Wv = (const float*)d_in[3];
  const float* bq = (const float*)d_in[4];
  const float* bk = (const float*)d_in[5];
  const float* bv = (const float*)d_in[6];
  // d_in[7] = mask; tril(ones) by construction -> causal hard-coded.
  float* out = (float*)d_out;

  char* ws = (char*)d_ws;
  bf16_t* Q  = (bf16_t*)(ws + 0);                       // 2 MiB
  bf16_t* K  = (bf16_t*)(ws + (size_t)2 * 1024 * 1024); // 2 MiB
  bf16_t* Vt = (bf16_t*)(ws + (size_t)4 * 1024 * 1024); // 2 MiB
  bf16_t* Wt = (bf16_t*)(ws + (size_t)6 * 1024 * 1024); // 384 KiB

  hipLaunchKernelGGL(prep_w_kernel, dim3(192), dim3(256), 0, stream, Wq, Wk, Wv, Wt);
  hipLaunchKernelGGL(qkv_proj_kernel, dim3(16384 / 32), dim3(256), 0, stream,
                     x, Wt, bq, bk, bv, Q, K, Vt);
  hipLaunchKernelGGL(attn_kernel, dim3(B_ * (S_ / 64)), dim3(1024), 0, stream, Q, K, Vt, out);
}

// Round 3
// 179.258 us; speedup vs baseline: 1.5894x; 1.0398x over previous
//
#include <hip/hip_runtime.h>
#include <hip/hip_bf16.h>
#include <cstdint>

typedef __bf16 bf16_t;
typedef __bf16 bf16x8 __attribute__((ext_vector_type(8)));
typedef float f32x4 __attribute__((ext_vector_type(4)));

#define B_ 4
#define S_ 4096
#define E_ 1024
#define L_ 64

__device__ __forceinline__ f32x4 mfma16(bf16x8 a, bf16x8 b, f32x4 c) {
  return __builtin_amdgcn_mfma_f32_16x16x32_bf16(a, b, c, 0, 0, 0);
}

// DPP rotate-reduce within 16-lane rows (VALU, no LDS traffic).
// row_ror:N ctrl = 0x120|N. Reduction over lr (lanes are lg*16+lr, so a DPP
// row == one lg group). Rotate-reduce ror{1,2,4,8} == full 16-lane reduce.
template <int CTRL>
__device__ __forceinline__ float dpp_max_step(float x) {
  int t = __builtin_amdgcn_update_dpp(0, __float_as_int(x), CTRL, 0xF, 0xF, true);
  return fmaxf(x, __int_as_float(t));
}
template <int CTRL>
__device__ __forceinline__ float dpp_add_step(float x) {
  int t = __builtin_amdgcn_update_dpp(0, __float_as_int(x), CTRL, 0xF, 0xF, true);
  return x + __int_as_float(t);
}
__device__ __forceinline__ float dpp_reduce_max16(float x) {
  x = dpp_max_step<0x121>(x);
  x = dpp_max_step<0x122>(x);
  x = dpp_max_step<0x124>(x);
  x = dpp_max_step<0x128>(x);
  return x;
}
__device__ __forceinline__ float dpp_reduce_add16(float x) {
  x = dpp_add_step<0x121>(x);
  x = dpp_add_step<0x122>(x);
  x = dpp_add_step<0x124>(x);
  x = dpp_add_step<0x128>(x);
  return x;
}

// ---- kernel 1: weights -> Wt bf16 [192][1024] (Wt[n][k] = W[k][n]) ----
__global__ void prep_w_kernel(const float* __restrict__ Wq, const float* __restrict__ Wk,
                              const float* __restrict__ Wv, bf16_t* __restrict__ Wt) {
  int n = blockIdx.x;  // 0..191
  const float* W = (n < 64) ? Wq : (n < 128 ? Wk : Wv);
  int col = n & 63;
  for (int k = threadIdx.x; k < E_; k += blockDim.x)
    Wt[(size_t)n * E_ + k] = (bf16_t)W[(size_t)k * L_ + col];
}

// ---- kernel 2: QKV projection via bf16 MFMA, fp32 accum ----
// 1024 blocks x 4 waves: block = 16-row strip; wave w covers cols w*48..w*48+47.
// Q,K stored [B*S][64] bf16 row-major; V stored transposed Vt[b][64][4096] bf16.
__global__ __launch_bounds__(256) void qkv_proj_kernel(
    const float* __restrict__ x, const bf16_t* __restrict__ Wt,
    const float* __restrict__ bq, const float* __restrict__ bk, const float* __restrict__ bv,
    bf16_t* __restrict__ Q, bf16_t* __restrict__ K, bf16_t* __restrict__ Vt) {
  const int w = threadIdx.x >> 6, l = threadIdx.x & 63;
  const int lr = l & 15, lg = l >> 4;
  const int m0 = blockIdx.x * 16;
  const int colbase = w * 48;  // 3 col-tiles of 16

  f32x4 acc[3];
#pragma unroll
  for (int t = 0; t < 3; ++t) acc[t] = f32x4{0.f, 0.f, 0.f, 0.f};

  const float* xrow = x + (size_t)(m0 + lr) * E_ + lg * 8;
#pragma unroll 4
  for (int kc = 0; kc < E_; kc += 32) {
    float4 a0 = *reinterpret_cast<const float4*>(xrow + kc);
    float4 a1 = *reinterpret_cast<const float4*>(xrow + kc + 4);
    bf16x8 a;
    a[0] = (bf16_t)a0.x; a[1] = (bf16_t)a0.y; a[2] = (bf16_t)a0.z; a[3] = (bf16_t)a0.w;
    a[4] = (bf16_t)a1.x; a[5] = (bf16_t)a1.y; a[6] = (bf16_t)a1.z; a[7] = (bf16_t)a1.w;
#pragma unroll
    for (int t = 0; t < 3; ++t) {
      bf16x8 b = *reinterpret_cast<const bf16x8*>(Wt + (size_t)(colbase + t * 16 + lr) * E_ + kc + lg * 8);
      acc[t] = mfma16(a, b, acc[t]);
    }
  }

#pragma unroll
  for (int t = 0; t < 3; ++t) {
    int ng = colbase + t * 16 + lr;  // 0..191 global out col (tile is mat-uniform)
    int mat = ng >> 6;
    int col = ng & 63;
    const float* bias = (mat == 0) ? bq : (mat == 1 ? bk : bv);
    float bb = bias[col];
#pragma unroll
    for (int r = 0; r < 4; ++r) {
      int mg = m0 + lg * 4 + r;  // global row (batch*4096 + s)
      float v = acc[t][r] + bb;
      if (mat == 0)      Q[(size_t)mg * L_ + col] = (bf16_t)v;
      else if (mat == 1) K[(size_t)mg * L_ + col] = (bf16_t)v;
      else {
        int batch = mg >> 12, s = mg & (S_ - 1);
        Vt[((size_t)batch * L_ + col) * S_ + s] = (bf16_t)v;
      }
    }
  }
}

// ---- kernel 3: causal flash attention, split-K x2 across blocks ----
// grid = 512: tile t = blockIdx>>1 (batch = t&3 -> XCD-affine), half h = blockIdx&1.
// 16 waves: strip r = w&3 (16 q-rows), chunk c = w>>2; wave handles kt ≡ 2c+h (mod 8).
// Output: UNNORMALIZED partial O + per-row (m,l) to workspace; combine kernel merges.
__global__ __launch_bounds__(1024) void attn_kernel(
    const bf16_t* __restrict__ Qg, const bf16_t* __restrict__ Kg,
    const bf16_t* __restrict__ Vt, float* __restrict__ Opart, float* __restrict__ mlpart) {
  __shared__ __align__(16) float od_lds[12 * 16 * 64];  // 48 KiB (doubles as P staging)
  __shared__ float ml_lds[16][16][2];

  const int w = threadIdx.x >> 6, l = threadIdx.x & 63;
  const int lr = l & 15, lg = l >> 4;
  const int r = w & 3, c = w >> 2;
  const int t = blockIdx.x >> 1, h = blockIdx.x & 1;
  const int batch = t & 3;       // consecutive blocks -> batch-affine XCDs
  const int qt = t >> 2;
  const int qrow = qt * 64 + r * 16;  // batch-local
  const size_t qbase = (size_t)batch * S_ + qrow;
  const bf16_t* Kb = Kg + (size_t)batch * S_ * L_;
  const bf16_t* Vb = Vt + (size_t)batch * L_ * S_;
  bf16_t* pw = reinterpret_cast<bf16_t*>(od_lds) + (size_t)w * (16 * 72);

  bf16x8 qa0 = *reinterpret_cast<const bf16x8*>(Qg + (qbase + lr) * L_ + lg * 8);
  bf16x8 qa1 = *reinterpret_cast<const bf16x8*>(Qg + (qbase + lr) * L_ + 32 + lg * 8);

  f32x4 o[4];
  float m[4], ssum[4];
#pragma unroll
  for (int rr = 0; rr < 4; ++rr) { o[rr] = f32x4{0.f, 0.f, 0.f, 0.f}; m[rr] = -1e30f; ssum[rr] = 0.f; }

  for (int kt = 2 * c + h; kt <= qt; kt += 8) {
    const int t0 = kt * 64;
    f32x4 st[4];
#pragma unroll
    for (int cf = 0; cf < 4; ++cf) st[cf] = f32x4{0.f, 0.f, 0.f, 0.f};
#pragma unroll
    for (int cf = 0; cf < 4; ++cf) {
      const bf16_t* krow = Kb + (size_t)(t0 + cf * 16 + lr) * L_ + lg * 8;
      st[cf] = mfma16(qa0, *reinterpret_cast<const bf16x8*>(krow), st[cf]);
      st[cf] = mfma16(qa1, *reinterpret_cast<const bf16x8*>(krow + 32), st[cf]);
    }
    const bool diag = (kt == qt);
    float p[4][4];  // [cf][reg]
#pragma unroll
    for (int rr = 0; rr < 4; ++rr) {
      const int qg = qrow + lg * 4 + rr;
      float rowmax = -1e30f;
#pragma unroll
      for (int cf = 0; cf < 4; ++cf) {
        float s = st[cf][rr] * 0.125f;  // 1/sqrt(64)
        if (diag && (t0 + cf * 16 + lr) > qg) s = -1e30f;
        p[cf][rr] = s;
        rowmax = fmaxf(rowmax, s);
      }
      rowmax = dpp_reduce_max16(rowmax);
      float mnew = fmaxf(m[rr], rowmax);
      float scale = __expf(m[rr] - mnew);
      float rs = 0.f;
#pragma unroll
      for (int cf = 0; cf < 4; ++cf) {
        float e = __expf(p[cf][rr] - mnew);
        p[cf][rr] = e;
        rs += e;
      }
      rs = dpp_reduce_add16(rs);
      ssum[rr] = ssum[rr] * scale + rs;
#pragma unroll
      for (int cf = 0; cf < 4; ++cf) o[cf][rr] *= scale;
      m[rr] = mnew;
    }
    // P (C-layout) -> LDS -> A-layout fragments (wave-private region)
#pragma unroll
    for (int rr = 0; rr < 4; ++rr)
#pragma unroll
      for (int cf = 0; cf < 4; ++cf)
        pw[(lg * 4 + rr) * 72 + cf * 16 + lr] = (bf16_t)p[cf][rr];
    bf16x8 pa0 = *reinterpret_cast<const bf16x8*>(pw + lr * 72 + lg * 8);
    bf16x8 pa1 = *reinterpret_cast<const bf16x8*>(pw + lr * 72 + 32 + lg * 8);
#pragma unroll
    for (int cf = 0; cf < 4; ++cf) {
      const bf16_t* vrow = Vb + (size_t)(cf * 16 + lr) * S_ + t0 + lg * 8;
      o[cf] = mfma16(pa0, *reinterpret_cast<const bf16x8*>(vrow), o[cf]);
      o[cf] = mfma16(pa1, *reinterpret_cast<const bf16x8*>(vrow + 32), o[cf]);
    }
  }

  if (lr == 0) {
#pragma unroll
    for (int rr = 0; rr < 4; ++rr) {
      ml_lds[w][lg * 4 + rr][0] = m[rr];
      ml_lds[w][lg * 4 + rr][1] = ssum[rr];
    }
  }
  __syncthreads();  // P-staging reads done; od region safe to overwrite
  if (c > 0) {
    float* dst = od_lds + (size_t)((c - 1) * 4 + r) * (16 * 64);
#pragma unroll
    for (int cf = 0; cf < 4; ++cf)
#pragma unroll
      for (int rr = 0; rr < 4; ++rr)
        dst[(lg * 4 + rr) * 64 + cf * 16 + lr] = o[cf][rr];
  }
  __syncthreads();
  if (c == 0) {
    float* Op = Opart + (size_t)(h * 256 + t) * 4096;
    float* mlp = mlpart + (size_t)(h * 256 + t) * 128;
#pragma unroll
    for (int rr = 0; rr < 4; ++rr) {
      int row = lg * 4 + rr;          // strip-local
      int grow = r * 16 + row;        // tile-local
      float M = m[rr];
      float mv[3];
#pragma unroll
      for (int cc = 1; cc < 4; ++cc) {
        mv[cc - 1] = ml_lds[cc * 4 + r][row][0];
        M = fmaxf(M, mv[cc - 1]);
      }
      float f0 = __expf(m[rr] - M);
      float Lsum = ssum[rr] * f0;
      float fc[3];
#pragma unroll
      for (int cc = 1; cc < 4; ++cc) {
        fc[cc - 1] = __expf(mv[cc - 1] - M);
        Lsum += ml_lds[cc * 4 + r][row][1] * fc[cc - 1];
      }
      if (lr == 0) { mlp[grow * 2] = M; mlp[grow * 2 + 1] = Lsum; }
#pragma unroll
      for (int cf = 0; cf < 4; ++cf) {
        float val = o[cf][rr] * f0;
#pragma unroll
        for (int cc = 1; cc < 4; ++cc)
          val += od_lds[(size_t)((cc - 1) * 4 + r) * (16 * 64) + row * 64 + cf * 16 + lr] * fc[cc - 1];
        Op[grow * 64 + cf * 16 + lr] = val;  // unnormalized
      }
    }
  }
}

// ---- kernel 4: merge the two split-K halves ----
__global__ __launch_bounds__(256) void combine_kernel(
    const float* __restrict__ Opart, const float* __restrict__ mlpart,
    float* __restrict__ out) {
  const int t = blockIdx.x;  // 0..255
  const int batch = t & 3, qt = t >> 2;
  const int tid = threadIdx.x;
  const int row = tid >> 2, c0 = (tid & 3) * 16;
  const float* ml0 = mlpart + ((size_t)(0 * 256 + t) * 64 + row) * 2;
  const float* ml1 = mlpart + ((size_t)(1 * 256 + t) * 64 + row) * 2;
  float m0 = ml0[0], l0 = ml0[1], m1 = ml1[0], l1 = ml1[1];
  float M = fmaxf(m0, m1);
  float f0 = __expf(m0 - M), f1 = __expf(m1 - M);
  float inv = 1.f / (l0 * f0 + l1 * f1);
  const float* O0 = Opart + (size_t)(0 * 256 + t) * 4096 + row * 64 + c0;
  const float* O1 = Opart + (size_t)(1 * 256 + t) * 4096 + row * 64 + c0;
  float* dst = out + ((size_t)batch * S_ + qt * 64 + row) * L_ + c0;
#pragma unroll
  for (int j = 0; j < 4; ++j) {
    float4 a = reinterpret_cast<const float4*>(O0)[j];
    float4 b = reinterpret_cast<const float4*>(O1)[j];
    float4 v;
    v.x = (a.x * f0 + b.x * f1) * inv;
    v.y = (a.y * f0 + b.y * f1) * inv;
    v.z = (a.z * f0 + b.z * f1) * inv;
    v.w = (a.w * f0 + b.w * f1) * inv;
    reinterpret_cast<float4*>(dst)[j] = v;
  }
}

extern "C" void kernel_launch(void* const* d_in, const int* in_sizes, int n_in,
                              void* d_out, int out_size, void* d_ws, size_t ws_size,
                              hipStream_t stream) {
  (void)in_sizes; (void)n_in; (void)out_size; (void)ws_size;
  const float* x  = (const float*)d_in[0];
  const float* Wq = (const float*)d_in[1];
  const float* Wk = (const float*)d_in[2];
  const float* Wv = (const float*)d_in[3];
  const float* bq = (const float*)d_in[4];
  const float* bk = (const float*)d_in[5];
  const float* bv = (const float*)d_in[6];
  // d_in[7] = mask; tril(ones) by construction -> causal hard-coded.
  float* out = (float*)d_out;

  char* ws = (char*)d_ws;
  bf16_t* Q   = (bf16_t*)(ws + 0);                        // 2 MiB
  bf16_t* K   = (bf16_t*)(ws + (size_t)2 * 1024 * 1024);  // 2 MiB
  bf16_t* Vt  = (bf16_t*)(ws + (size_t)4 * 1024 * 1024);  // 2 MiB
  bf16_t* Wt  = (bf16_t*)(ws + (size_t)6 * 1024 * 1024);  // 384 KiB
  float* Opart = (float*)(ws + (size_t)7 * 1024 * 1024);  // 8 MiB (512 x 64 x 64 f32)
  float* mlpart = (float*)(ws + (size_t)15 * 1024 * 1024); // 256 KiB

  hipLaunchKernelGGL(prep_w_kernel, dim3(192), dim3(256), 0, stream, Wq, Wk, Wv, Wt);
  hipLaunchKernelGGL(qkv_proj_kernel, dim3(16384 / 16), dim3(256), 0, stream,
                     x, Wt, bq, bk, bv, Q, K, Vt);
  hipLaunchKernelGGL(attn_kernel, dim3(2 * B_ * (S_ / 64)), dim3(1024), 0, stream,
                     Q, K, Vt, Opart, mlpart);
  hipLaunchKernelGGL(combine_kernel, dim3(B_ * (S_ / 64)), dim3(256), 0, stream,
                     Opart, mlpart, out);
}

// Round 4
// 152.562 us; speedup vs baseline: 1.8675x; 1.1750x over previous
//
#include <hip/hip_runtime.h>
#include <hip/hip_bf16.h>
#include <cstdint>

typedef __bf16 bf16_t;
typedef __bf16 bf16x8 __attribute__((ext_vector_type(8)));
typedef float f32x4 __attribute__((ext_vector_type(4)));

#define B_ 4
#define S_ 4096
#define E_ 1024
#define L_ 64

__device__ __forceinline__ f32x4 mfma16(bf16x8 a, bf16x8 b, f32x4 c) {
  return __builtin_amdgcn_mfma_f32_16x16x32_bf16(a, b, c, 0, 0, 0);
}

// DPP rotate-reduce within 16-lane rows (VALU, no LDS traffic).
template <int CTRL>
__device__ __forceinline__ float dpp_max_step(float x) {
  int t = __builtin_amdgcn_update_dpp(0, __float_as_int(x), CTRL, 0xF, 0xF, true);
  return fmaxf(x, __int_as_float(t));
}
template <int CTRL>
__device__ __forceinline__ float dpp_add_step(float x) {
  int t = __builtin_amdgcn_update_dpp(0, __float_as_int(x), CTRL, 0xF, 0xF, true);
  return x + __int_as_float(t);
}
__device__ __forceinline__ float dpp_reduce_max16(float x) {
  x = dpp_max_step<0x121>(x);
  x = dpp_max_step<0x122>(x);
  x = dpp_max_step<0x124>(x);
  x = dpp_max_step<0x128>(x);
  return x;
}
__device__ __forceinline__ float dpp_reduce_add16(float x) {
  x = dpp_add_step<0x121>(x);
  x = dpp_add_step<0x122>(x);
  x = dpp_add_step<0x124>(x);
  x = dpp_add_step<0x128>(x);
  return x;
}

// ---- kernel 1: weights -> Wt bf16 [192][1024] (Wt[n][k] = W[k][n]) ----
__global__ void prep_w_kernel(const float* __restrict__ Wq, const float* __restrict__ Wk,
                              const float* __restrict__ Wv, bf16_t* __restrict__ Wt) {
  int n = blockIdx.x;  // 0..191
  const float* W = (n < 64) ? Wq : (n < 128 ? Wk : Wv);
  int col = n & 63;
  for (int k = threadIdx.x; k < E_; k += blockDim.x)
    Wt[(size_t)n * E_ + k] = (bf16_t)W[(size_t)k * L_ + col];
}

// ---- kernel 2: QKV projection via bf16 MFMA, fp32 accum ----
// 256 blocks x 12 waves: block = 64 rows; wave = (rowgrp w&3, colgrp w>>2).
// colgrp 0/1/2 -> Q/K/V (wave-uniform output matrix), 64 cols each.
// Q,K stored [B*S][64] bf16 row-major; V stored transposed Vt[b][64][4096] bf16.
__global__ __launch_bounds__(768) void qkv_proj_kernel(
    const float* __restrict__ x, const bf16_t* __restrict__ Wt,
    const float* __restrict__ bq, const float* __restrict__ bk, const float* __restrict__ bv,
    bf16_t* __restrict__ Q, bf16_t* __restrict__ K, bf16_t* __restrict__ Vt) {
  const int w = threadIdx.x >> 6, l = threadIdx.x & 63;
  const int lr = l & 15, lg = l >> 4;
  const int rowgrp = w & 3;   // 0..3
  const int colgrp = w >> 2;  // 0..2 -> Q,K,V
  const int m0 = blockIdx.x * 64 + rowgrp * 16;

  f32x4 acc[4];
#pragma unroll
  for (int t = 0; t < 4; ++t) acc[t] = f32x4{0.f, 0.f, 0.f, 0.f};

  const float* xrow = x + (size_t)(m0 + lr) * E_ + lg * 8;
  const bf16_t* wbase = Wt + (size_t)(colgrp * 64 + lr) * E_ + lg * 8;
#pragma unroll 4
  for (int kc = 0; kc < E_; kc += 32) {
    float4 a0 = *reinterpret_cast<const float4*>(xrow + kc);
    float4 a1 = *reinterpret_cast<const float4*>(xrow + kc + 4);
    bf16x8 a;
    a[0] = (bf16_t)a0.x; a[1] = (bf16_t)a0.y; a[2] = (bf16_t)a0.z; a[3] = (bf16_t)a0.w;
    a[4] = (bf16_t)a1.x; a[5] = (bf16_t)a1.y; a[6] = (bf16_t)a1.z; a[7] = (bf16_t)a1.w;
#pragma unroll
    for (int t = 0; t < 4; ++t) {
      bf16x8 b = *reinterpret_cast<const bf16x8*>(wbase + (size_t)t * 16 * E_ + kc);
      acc[t] = mfma16(a, b, acc[t]);
    }
  }

  const float* bias = (colgrp == 0) ? bq : (colgrp == 1 ? bk : bv);
#pragma unroll
  for (int t = 0; t < 4; ++t) {
    int col = t * 16 + lr;  // 0..63 within this matrix
    float bb = bias[col];
#pragma unroll
    for (int r = 0; r < 4; ++r) {
      int mg = m0 + lg * 4 + r;  // global row (batch*4096 + s)
      float v = acc[t][r] + bb;
      if (colgrp == 0)      Q[(size_t)mg * L_ + col] = (bf16_t)v;
      else if (colgrp == 1) K[(size_t)mg * L_ + col] = (bf16_t)v;
      else {
        int batch = mg >> 12, s = mg & (S_ - 1);
        Vt[((size_t)batch * L_ + col) * S_ + s] = (bf16_t)v;
      }
    }
  }
}

// ---- kernel 3: causal flash attention ----
// grid = 1024 small blocks: block = ONE 16-row q-strip, 4 waves = split-K chunks
// (wave c handles kt ≡ c mod 4), merged in LDS at the end -> direct output,
// no global combine. LPT launch order: qt descends with blockIdx (longest first).
__global__ __launch_bounds__(256) void attn_kernel(
    const bf16_t* __restrict__ Qg, const bf16_t* __restrict__ Kg,
    const bf16_t* __restrict__ Vt, float* __restrict__ out) {
  __shared__ __align__(16) bf16_t p_lds[4][16 * 72];  // per-wave P staging (9 KiB)
  __shared__ float od_lds[3][16][65];                  // c=1..3 partial O (12.2 KiB)
  __shared__ float ml_lds[3][16][2];                   // c=1..3 (m,l)

  const int c = threadIdx.x >> 6, l = threadIdx.x & 63;
  const int lr = l & 15, lg = l >> 4;
  const int u = blockIdx.x;
  const int qt = 63 - (u >> 4);        // LPT: big tiles first
  const int batch = u & 3;
  const int strip = (u >> 2) & 3;
  const int qrow = qt * 64 + strip * 16;  // batch-local
  const size_t qbase = (size_t)batch * S_ + qrow;
  const bf16_t* Kb = Kg + (size_t)batch * S_ * L_;
  const bf16_t* Vb = Vt + (size_t)batch * L_ * S_;
  bf16_t* pw = p_lds[c];

  bf16x8 qa0 = *reinterpret_cast<const bf16x8*>(Qg + (qbase + lr) * L_ + lg * 8);
  bf16x8 qa1 = *reinterpret_cast<const bf16x8*>(Qg + (qbase + lr) * L_ + 32 + lg * 8);

  f32x4 o[4];
  float m[4], ssum[4];
#pragma unroll
  for (int rr = 0; rr < 4; ++rr) { o[rr] = f32x4{0.f, 0.f, 0.f, 0.f}; m[rr] = -1e30f; ssum[rr] = 0.f; }

  for (int kt = c; kt <= qt; kt += 4) {
    const int t0 = kt * 64;
    f32x4 st[4];
#pragma unroll
    for (int cf = 0; cf < 4; ++cf) st[cf] = f32x4{0.f, 0.f, 0.f, 0.f};
#pragma unroll
    for (int cf = 0; cf < 4; ++cf) {
      const bf16_t* krow = Kb + (size_t)(t0 + cf * 16 + lr) * L_ + lg * 8;
      st[cf] = mfma16(qa0, *reinterpret_cast<const bf16x8*>(krow), st[cf]);
      st[cf] = mfma16(qa1, *reinterpret_cast<const bf16x8*>(krow + 32), st[cf]);
    }
    const bool diag = (kt == qt);
    float p[4][4];  // [cf][reg]
#pragma unroll
    for (int rr = 0; rr < 4; ++rr) {
      const int qg = qrow + lg * 4 + rr;
      float rowmax = -1e30f;
#pragma unroll
      for (int cf = 0; cf < 4; ++cf) {
        float s = st[cf][rr] * 0.125f;  // 1/sqrt(64)
        if (diag && (t0 + cf * 16 + lr) > qg) s = -1e30f;
        p[cf][rr] = s;
        rowmax = fmaxf(rowmax, s);
      }
      rowmax = dpp_reduce_max16(rowmax);
      float mnew = fmaxf(m[rr], rowmax);
      float scale = __expf(m[rr] - mnew);
      float rs = 0.f;
#pragma unroll
      for (int cf = 0; cf < 4; ++cf) {
        float e = __expf(p[cf][rr] - mnew);
        p[cf][rr] = e;
        rs += e;
      }
      rs = dpp_reduce_add16(rs);
      ssum[rr] = ssum[rr] * scale + rs;
#pragma unroll
      for (int cf = 0; cf < 4; ++cf) o[cf][rr] *= scale;
      m[rr] = mnew;
    }
    // P (C-layout) -> LDS -> A-layout fragments (wave-private region, no barrier)
#pragma unroll
    for (int rr = 0; rr < 4; ++rr)
#pragma unroll
      for (int cf = 0; cf < 4; ++cf)
        pw[(lg * 4 + rr) * 72 + cf * 16 + lr] = (bf16_t)p[cf][rr];
    bf16x8 pa0 = *reinterpret_cast<const bf16x8*>(pw + lr * 72 + lg * 8);
    bf16x8 pa1 = *reinterpret_cast<const bf16x8*>(pw + lr * 72 + 32 + lg * 8);
#pragma unroll
    for (int cf = 0; cf < 4; ++cf) {
      const bf16_t* vrow = Vb + (size_t)(cf * 16 + lr) * S_ + t0 + lg * 8;
      o[cf] = mfma16(pa0, *reinterpret_cast<const bf16x8*>(vrow), o[cf]);
      o[cf] = mfma16(pa1, *reinterpret_cast<const bf16x8*>(vrow + 32), o[cf]);
    }
  }

  // chunks c=1..3 export unnormalized partials; c=0 merges and writes out.
  if (c > 0) {
    if (lr == 0) {
#pragma unroll
      for (int rr = 0; rr < 4; ++rr) {
        ml_lds[c - 1][lg * 4 + rr][0] = m[rr];
        ml_lds[c - 1][lg * 4 + rr][1] = ssum[rr];
      }
    }
#pragma unroll
    for (int cf = 0; cf < 4; ++cf)
#pragma unroll
      for (int rr = 0; rr < 4; ++rr)
        od_lds[c - 1][lg * 4 + rr][cf * 16 + lr] = o[cf][rr];
  }
  __syncthreads();
  if (c == 0) {
#pragma unroll
    for (int rr = 0; rr < 4; ++rr) {
      const int row = lg * 4 + rr;
      float M = m[rr];
      float mv[3];
#pragma unroll
      for (int cc = 0; cc < 3; ++cc) {
        mv[cc] = ml_lds[cc][row][0];
        M = fmaxf(M, mv[cc]);
      }
      float f0 = __expf(m[rr] - M);
      float Lsum = ssum[rr] * f0;
      float fc[3];
#pragma unroll
      for (int cc = 0; cc < 3; ++cc) {
        fc[cc] = __expf(mv[cc] - M);
        Lsum += ml_lds[cc][row][1] * fc[cc];
      }
      float invL = 1.f / Lsum;
#pragma unroll
      for (int cf = 0; cf < 4; ++cf) {
        float val = o[cf][rr] * f0;
#pragma unroll
        for (int cc = 0; cc < 3; ++cc)
          val += od_lds[cc][row][cf * 16 + lr] * fc[cc];
        out[(qbase + row) * L_ + cf * 16 + lr] = val * invL;
      }
    }
  }
}

extern "C" void kernel_launch(void* const* d_in, const int* in_sizes, int n_in,
                              void* d_out, int out_size, void* d_ws, size_t ws_size,
                              hipStream_t stream) {
  (void)in_sizes; (void)n_in; (void)out_size; (void)ws_size;
  const float* x  = (const float*)d_in[0];
  const float* Wq = (const float*)d_in[1];
  const float* Wk = (const float*)d_in[2];
  const float* Wv = (const float*)d_in[3];
  const float* bq = (const float*)d_in[4];
  const float* bk = (const float*)d_in[5];
  const float* bv = (const float*)d_in[6];
  // d_in[7] = mask; tril(ones) by construction -> causal hard-coded.
  float* out = (float*)d_out;

  char* ws = (char*)d_ws;
  bf16_t* Q  = (bf16_t*)(ws + 0);                        // 2 MiB
  bf16_t* K  = (bf16_t*)(ws + (size_t)2 * 1024 * 1024);  // 2 MiB
  bf16_t* Vt = (bf16_t*)(ws + (size_t)4 * 1024 * 1024);  // 2 MiB
  bf16_t* Wt = (bf16_t*)(ws + (size_t)6 * 1024 * 1024);  // 384 KiB

  hipLaunchKernelGGL(prep_w_kernel, dim3(192), dim3(256), 0, stream, Wq, Wk, Wv, Wt);
  hipLaunchKernelGGL(qkv_proj_kernel, dim3(16384 / 64), dim3(768), 0, stream,
                     x, Wt, bq, bk, bv, Q, K, Vt);
  hipLaunchKernelGGL(attn_kernel, dim3(4 * B_ * (S_ / 64)), dim3(256), 0, stream,
                     Q, K, Vt, out);
}